// Round 1
// 112.422 us; speedup vs baseline: 1.0757x; 1.0757x over previous
//
#include <hip/hip_runtime.h>

// Table-based structure (R12): s(x) = w3.leaky(W2.leaky(w1 x + b1) + b2) + b3
// is a 1-D piecewise-linear function of the scalar x (ELU applied after).
// Build an NT-point uniform table of s over [lb, XMAX] per d (exact f32 MLP
// evals), then each of the 8.4M point evals = linear interp from LDS + elu.
// R16: integrate reads u as float2 (lane owns points 2l, 2l+1 — one 8B
// coalesced load per b), grid 2048 (8 blocks/CU backfill). Bench is now
// ~80% fixed harness fills; controllable content ~25 us vs ~8 us floor.
// R17: (a) wave reduction via DPP (row_shr/row_bcast, pure VALU) instead of
// 6x ds_swizzle — the LDS pipe is per-CU (shared by 4 SIMDs) and the
// butterfly was ~3/4 of integrate's DS ops; (b) build_table 64->256 blocks
// (4x shorter ds_read chain, all CUs busy) with W2 stride padded to 76
// floats so the 16 concurrently-read rows hit distinct bank groups.
#define NT 2048
#define XMAX 8.0f

// ws layout (floats): [0, 4096) = tables (d=0, d=1)

// Canonical GCN wave64 sum via DPP: result lands in lane 63. Pure VALU —
// zero LDS-pipe traffic (vs ds_swizzle shuffles).
__device__ __forceinline__ float wave_sum_lane63(float v) {
#define DPP_ADD(ctrl)                                                         \
    v += __int_as_float(__builtin_amdgcn_update_dpp(                          \
        0, __float_as_int(v), (ctrl), 0xf, 0xf, false))
    DPP_ADD(0x111);  // row_shr:1
    DPP_ADD(0x112);  // row_shr:2
    DPP_ADD(0x114);  // row_shr:4
    DPP_ADD(0x118);  // row_shr:8   -> lane15 of each row has row sum
    DPP_ADD(0x142);  // row_bcast:15 -> lane31 = rows0+1, lane63 += row2
    DPP_ADD(0x143);  // row_bcast:31 -> lane63 = total
#undef DPP_ADD
    return v;
}

#define W2STRIDE 76  // 304 B: 16B-aligned float4 rows, banks spread (12f % 32)

__global__ __launch_bounds__(256) void build_table(
    const float* __restrict__ w01, const float* __restrict__ b01,
    const float* __restrict__ w02, const float* __restrict__ b02,
    const float* __restrict__ w03, const float* __restrict__ b03,
    const float* __restrict__ w11, const float* __restrict__ b11,
    const float* __restrict__ w12, const float* __restrict__ b12,
    const float* __restrict__ w13, const float* __restrict__ b13,
    const int* __restrict__ lbp, float* __restrict__ T)
{
    __shared__ float W2s[64 * W2STRIDE];
    __shared__ float w1s[64], b1s[64], b2s[64], w3s[64];

    const int tid = threadIdx.x;
    // 256 blocks: d = bid&1; 128 chunks x 16 entries per d; 16 lanes per entry
    const int d  = blockIdx.x & 1;
    const int e0 = (blockIdx.x >> 1) * 16;

    const float* w1p = d ? w11 : w01;
    const float* b1p = d ? b11 : b01;
    const float* w2p = d ? w12 : w02;
    const float* b2p = d ? b12 : b02;
    const float* w3p = d ? w13 : w03;
    const float  b3  = (d ? b13 : b03)[0];

    // stage W2 coalesced (16 rounds), padded row stride
    #pragma unroll
    for (int j = 0; j < 16; ++j) {
        const int idx = tid + 256 * j;
        W2s[(idx >> 6) * W2STRIDE + (idx & 63)] = w2p[idx];
    }
    if (tid < 64) {
        w1s[tid] = w1p[tid];
        b1s[tid] = b1p[tid];
        b2s[tid] = b2p[tid];
        w3s[tid] = w3p[tid];
    }
    __syncthreads();

    const int e   = e0 + (tid >> 4);   // table entry
    const int sub = tid & 15;          // f-range selector (4 rows each)

    const float lb = (float)lbp[0];
    const float delta = (XMAX - lb) / (float)(NT - 1);
    const float x = fmaf((float)e, delta, lb);

    // h1 fully in registers (full unroll — partial unroll scratch-spills, R13)
    float h1[64];
    #pragma unroll
    for (int k = 0; k < 64; ++k) {
        const float t = fmaf(x, w1s[k], b1s[k]);
        h1[k] = fmaxf(t, 0.01f * t);   // leaky_relu
    }

    float s = 0.0f;
    #pragma unroll
    for (int ff = 0; ff < 4; ++ff) {
        const int f = (sub << 2) + ff;
        const float4* row = (const float4*)&W2s[f * W2STRIDE];
        float a = b2s[f];
        #pragma unroll
        for (int k4 = 0; k4 < 16; ++k4) {
            const float4 w = row[k4];   // ds_read_b128, rows bank-spread
            a = fmaf(w.x, h1[4 * k4 + 0], a);
            a = fmaf(w.y, h1[4 * k4 + 1], a);
            a = fmaf(w.z, h1[4 * k4 + 2], a);
            a = fmaf(w.w, h1[4 * k4 + 3], a);
        }
        s = fmaf(fmaxf(a, 0.01f * a), w3s[f], s);
    }

    // combine the 16 f-ranges (within 16-lane groups)
    s += __shfl_xor(s, 1);
    s += __shfl_xor(s, 2);
    s += __shfl_xor(s, 4);
    s += __shfl_xor(s, 8);
    if (sub == 0) T[d * NT + e] = s + b3;
}

// Block = 16 b's, both d's: wave w -> d = w&1, b-half = w>>1 (8 b's each).
// Both tables staged to LDS (16 KB). Per b: lane owns points 2l and 2l+1
// (one float2 u-load); interp + elu; DPP wave reduce (lane 63); d=0/d=1
// combined through LDS and stored directly with bias (no memset, no atomics).
// z/u prefetched one b ahead (proven load-bearing, R7).
__global__ __launch_bounds__(256) void integrate_tab(
    const float* __restrict__ zin, const float* __restrict__ uin,
    const float* __restrict__ Tg, const int* __restrict__ lbp,
    const float* __restrict__ biasp, float* __restrict__ out)
{
    __shared__ float Ts[2][NT];
    __shared__ float lds_hz[4][8];

    const int tid  = threadIdx.x;
    const int lane = tid & 63;
    const int wave = tid >> 6;
    const int d    = wave & 1;
    const int bg   = wave >> 1;
    const int b0 = blockIdx.x * 16 + bg * 8;

    const float lb = (float)lbp[0];
    const float scale = (float)(NT - 1) / (XMAX - lb);
    const float biasv = biasp[0];

    // stage both tables (coalesced, 16 rounds total)
    #pragma unroll
    for (int j = 0; j < 2 * NT / 256; ++j)
        ((float*)Ts)[tid + j * 256] = Tg[tid + j * 256];
    __syncthreads();

    const float* Td = Ts[d];
    const float n0 = (float)(2 * lane);
    const float n1 = (float)(2 * lane + 1);
    const bool last = (lane == 63);   // point 127 has no jitter

    // prefetch b0 (u as one float2 per lane)
    float z_n = zin[b0 * 2 + d];
    float2 u_n;
    {
        const float* ub = uin + (size_t)(b0 * 2 + d) * 127;
        u_n.x = ub[2 * lane];
        u_n.y = last ? 0.0f : ub[2 * lane + 1];
    }

    #pragma unroll 1
    for (int i = 0; i < 8; ++i) {
        const float zv = z_n;
        const float2 uu = u_n;

        // prefetch next b
        const int bn = b0 + ((i < 7) ? i + 1 : 7);
        z_n = zin[bn * 2 + d];
        {
            const float* ub = uin + (size_t)(bn * 2 + d) * 127;
            u_n.x = ub[2 * lane];
            u_n.y = last ? 0.0f : ub[2 * lane + 1];
        }

        const float ds  = (fmaxf(zv, lb) - lb) * (1.0f / 127.0f);
        const float dsc = ds * scale;
        const float t0 = (n0 + uu.x) * dsc;
        const float t1 = (n1 + uu.y) * dsc;

        int i0 = (int)t0; i0 = min(i0, NT - 2);
        int i1 = (int)t1; i1 = min(i1, NT - 2);
        const float f0 = t0 - (float)i0;
        const float f1 = t1 - (float)i1;

        const float a0 = Td[i0], a0b = Td[i0 + 1];   // fuses to ds_read2_b32
        const float a1 = Td[i1], a1b = Td[i1 + 1];
        const float s0 = fmaf(f0, a0b - a0, a0);
        const float s1 = fmaf(f1, a1b - a1, a1);

        // elu(s)+1 = s>0 ? s+1 : exp(s)
        const float e0 = __builtin_amdgcn_exp2f(s0 * 1.4426950408889634f);
        const float e1 = __builtin_amdgcn_exp2f(s1 * 1.4426950408889634f);
        float acc = ((s0 > 0.0f) ? (s0 + 1.0f) : e0)
                  + ((s1 > 0.0f) ? (s1 + 1.0f) : e1);

        // wave-wide reduce (covers n = 0..127) — pure VALU via DPP
        acc = wave_sum_lane63(acc);

        if (lane == 63) lds_hz[wave][i] = acc * ds;
    }

    __syncthreads();
    if (tid < 16) {
        const int g = tid >> 3, l = tid & 7;
        out[blockIdx.x * 16 + g * 8 + l] = lds_hz[2 * g][l] + lds_hz[2 * g + 1][l] + biasv;
    }
}

extern "C" void kernel_launch(void* const* d_in, const int* in_sizes, int n_in,
                              void* d_out, int out_size, void* d_ws, size_t ws_size,
                              hipStream_t stream) {
    const float* z    = (const float*)d_in[0];
    const float* u    = (const float*)d_in[1];
    const float* w0_1 = (const float*)d_in[2];
    const float* b0_1 = (const float*)d_in[3];
    const float* w0_2 = (const float*)d_in[4];
    const float* b0_2 = (const float*)d_in[5];
    const float* w0_3 = (const float*)d_in[6];
    const float* b0_3 = (const float*)d_in[7];
    const float* w1_1 = (const float*)d_in[8];
    const float* b1_1 = (const float*)d_in[9];
    const float* w1_2 = (const float*)d_in[10];
    const float* b1_2 = (const float*)d_in[11];
    const float* w1_3 = (const float*)d_in[12];
    const float* b1_3 = (const float*)d_in[13];
    const float* bias = (const float*)d_in[14];
    const int*   lbp  = (const int*)d_in[16];

    float* T = (float*)d_ws;   // 2 * 2048 floats

    build_table<<<dim3(256), dim3(256), 0, stream>>>(
        w0_1, b0_1, w0_2, b0_2, w0_3, b0_3,
        w1_1, b1_1, w1_2, b1_2, w1_3, b1_3,
        lbp, T);

    integrate_tab<<<dim3(2048), dim3(256), 0, stream>>>(z, u, T, lbp, bias, (float*)d_out);
}